// Round 11
// baseline (158.850 us; speedup 1.0000x reference)
//
#include <hip/hip_runtime.h>
#include <math.h>

#define B_  8
#define N_  128
#define T_  256
#define L_  32
#define H_  128
#define TT_ 224   // T - L

typedef float f4    __attribute__((ext_vector_type(4)));
typedef float f32x4 __attribute__((ext_vector_type(4)));
typedef short bf16x8 __attribute__((ext_vector_type(8)));

#define L2E_  1.4426950408889634f
#define L2E2_ 2.8853900817779268f

__device__ __forceinline__ unsigned pk2bf(float a, float b) {   // RNE bf16 pack
    unsigned ua = __float_as_uint(a), ub = __float_as_uint(b);
    ua = (ua + 0x7FFFu + ((ua >> 16) & 1u)) >> 16;
    ub = (ub + 0x7FFFu + ((ub >> 16) & 1u)) >> 16;
    return ua | (ub << 16);
}
// 2^x and 2^-x via raw v_exp_f32 (neg folded as src modifier). Weights/biases
// are pre-scaled by log2e (gates i,o) / 2*log2e (gate g) in k_pre, so the
// exp-argument muls vanish from the hot loop.
__device__ __forceinline__ float aexp2(float x) {
    float r; asm("v_exp_f32 %0, %1" : "=v"(r) : "v"(x)); return r;
}
__device__ __forceinline__ float aexp2n(float x) {
    float r; asm("v_exp_f32 %0, -%1" : "=v"(r) : "v"(x)); return r;
}

// ---------------------------------------------------------------------------
// Kernel 0, grid (N, 7) x 256:
//  y=0..5: W_ih -> bf16 W3sw pre-swizzled per-lane MFMA B-frag order,
//          PRE-SCALED: gate i,o rows x log2e; gate g rows x 2*log2e.
//  y=6:    wsum / bsum / fused bias (bias same pre-scale per gate).
// ---------------------------------------------------------------------------
__global__ __launch_bounds__(256)
void k_pre(const float* __restrict__ W_ih, const float* __restrict__ W_fc,
           const float* __restrict__ b_ih, const float* __restrict__ b_hh,
           const float* __restrict__ b_fc,
           unsigned short* __restrict__ W3sw, float* __restrict__ wsum,
           float* __restrict__ bsum, float* __restrict__ bia_g) {
    const int n   = blockIdx.x;
    const int pid = blockIdx.y;   // 0..6
    const int tid = threadIdx.x;
    if (pid < 6) {
        const int idx  = pid * 256 + tid;          // 0..1535
        const int fg   = idx >> 6;                 // 0..23
        const int lane = idx & 63;
        const int col  = lane & 15, quad = lane >> 4;
        const int g    = fg % 3, ht = fg / 3;
        const int r    = g * 128 + ht * 16 + col;
        const int sr   = r + (r >= 128 ? 128 : 0);
        const float sc = (g == 1) ? L2E2_ : L2E_;
        const f4* src = (const f4*)(W_ih + (size_t)n * 512 * L_ + sr * L_ + quad * 8);
        f4 v0 = src[0] * sc, v1 = src[1] * sc;
        uint4 out;
        out.x = pk2bf(v0.x, v0.y); out.y = pk2bf(v0.z, v0.w);
        out.z = pk2bf(v1.x, v1.y); out.w = pk2bf(v1.z, v1.w);
        *(uint4*)&W3sw[((size_t)n * 1536 + idx) * 8] = out;
    } else {
        __shared__ f4 part[8][32];
        __shared__ float bp[2];
        {   // wsum: thread (jg=tid>>5, h4=tid&31) sums 16 j
            const int h4 = tid & 31, jg = tid >> 5;
            const f4* Wf = (const f4*)(W_fc + (size_t)n * N_ * H_) + (size_t)jg * 16 * 32 + h4;
            f4 s = {0.f, 0.f, 0.f, 0.f};
            #pragma unroll
            for (int j = 0; j < 16; ++j) s += Wf[j * 32];
            part[jg][h4] = s;
        }
        if (tid < 128) {   // bsum partials
            float bv = b_fc[n * N_ + tid];
            #pragma unroll
            for (int off = 32; off > 0; off >>= 1) bv += __shfl_down(bv, off, 64);
            if ((tid & 63) == 0) bp[tid >> 6] = bv;
        }
        for (int i = tid; i < 384; i += 256) {
            const int sr = i + (i >= 128 ? 128 : 0);
            const float sc = (i >= 128 && i < 256) ? L2E2_ : L2E_;
            bia_g[n * 384 + i] =
                (b_ih[(size_t)n * 512 + sr] + b_hh[(size_t)n * 512 + sr]) * sc;
        }
        __syncthreads();
        if (tid < 32) {
            f4 s = part[0][tid];
            #pragma unroll
            for (int jg = 1; jg < 8; ++jg) s += part[jg][tid];
            *(f4*)&wsum[n * H_ + tid * 4] = s;
        }
        if (tid == 0) bsum[n] = bp[0] + bp[1];
    }
}

// ---------------------------------------------------------------------------
// Kernel 1: grid (N, B, 2) — t-range SPLIT in half (7 ttiles each) so
// 2048 blocks = 8 blocks/CU (R10's 1024 = exactly 4/CU left VALUBusy at 53%
// with a ~24 us issue floor; doubling resident waves hides the bubbles).
// amdgpu_waves_per_eu(8) pins VGPR<=64 so all 8 waves/SIMD are resident.
// G epilogue moved to k_g (Hd/Dinv now per-half partials in workspace).
// Activations use pre-scaled exp2 (v_exp_f32 asm, neg as src modifier).
// ---------------------------------------------------------------------------
__global__ __launch_bounds__(256)
__attribute__((amdgpu_waves_per_eu(8)))
void k_main(const float* __restrict__ x,
            const unsigned short* __restrict__ W3sw,
            const float* __restrict__ bia_g,
            const float* __restrict__ wsum, const float* __restrict__ bsum,
            float* __restrict__ Hd_part, float* __restrict__ Dinv_part,
            float* __restrict__ xhat) {
    const int n    = blockIdx.x;
    const int b    = blockIdx.y;
    const int half = blockIdx.z;
    const int tid  = threadIdx.x;
    const int w    = tid >> 6;    // wave 0..3
    const int lane = tid & 63;
    const int col  = lane & 15;   // MFMA m/n index
    const int quad = lane >> 4;   // MFMA k-group / row-group

    __shared__ float xs[258];
    __shared__ unsigned xeo[2][128];   // bf16 pairs: [0]=even-start, [1]=shift-1
    __shared__ float xr_loc[112];
    __shared__ uint4 xA[7 * 64];       // per-lane A-frags for this half, 7 KB
    __shared__ float xh_part[4][112];
    __shared__ float red[4];

    // ---- B-frags: 6 coalesced 16B loads (pre-swizzled, pre-scaled) ----
    const uint4* wsw = (const uint4*)W3sw + (size_t)n * 24 * 64 + lane;
    union { uint4 u; bf16x8 v; } bfr[2][3];
    float biaL[2][3], wshL[2];
    #pragma unroll
    for (int ht2 = 0; ht2 < 2; ++ht2) {
        const int ht = 2 * w + ht2;
        #pragma unroll
        for (int g = 0; g < 3; ++g) {
            bfr[ht2][g].u = wsw[(size_t)(ht * 3 + g) * 64];
            biaL[ht2][g]  = bia_g[n * 384 + g * 128 + ht * 16 + col];
        }
        wshL[ht2] = wsum[n * H_ + ht * 16 + col];
    }
    const float bsum_n = bsum[n];

    // ---- stage x (full row; cheap), xr for this half, parity pairs ----
    xs[tid] = x[((size_t)b * N_ + n) * T_ + tid];
    if (tid < 2) xs[256 + tid] = 0.f;
    __syncthreads();
    if (tid < 112) xr_loc[tid] = 1.0f / xs[L_ + half * 112 + tid];
    if (tid < 128) {
        xeo[0][tid] = pk2bf(xs[2 * tid],     xs[2 * tid + 1]);
        xeo[1][tid] = pk2bf(xs[2 * tid + 1], xs[2 * tid + 2]);
    }
    __syncthreads();
    // ---- pre-build per-lane A-frags for this half's 7 ttiles ----
    for (int e = tid; e < 7 * 64; e += 256) {
        const int tt = e >> 6, ln = e & 63;
        const int s  = (half * 7 + tt) * 16 + (ln & 15) + (ln >> 4) * 8;
        const int p  = s & 1, base = s >> 1;
        uint4 v;
        v.x = xeo[p][base + 0]; v.y = xeo[p][base + 1];
        v.z = xeo[p][base + 2]; v.w = xeo[p][base + 3];
        xA[e] = v;
    }
    __syncthreads();

    float hd_acc[2] = {0.f, 0.f};
    const f32x4 zero4 = {0.f, 0.f, 0.f, 0.f};

    #pragma unroll 2
    for (int tt = 0; tt < 7; ++tt) {
        union { uint4 u; bf16x8 v; } af;
        af.u = xA[tt * 64 + lane];          // one clean ds_read_b128

        const f4 xr4 = *(const f4*)&xr_loc[tt * 16 + quad * 4];
        float px[4] = {0.f, 0.f, 0.f, 0.f};

        #pragma unroll
        for (int ht2 = 0; ht2 < 2; ++ht2) {
            f32x4 ai = __builtin_amdgcn_mfma_f32_16x16x32_bf16(af.v, bfr[ht2][0].v, zero4, 0, 0, 0);
            f32x4 ag = __builtin_amdgcn_mfma_f32_16x16x32_bf16(af.v, bfr[ht2][1].v, zero4, 0, 0, 0);
            f32x4 ao = __builtin_amdgcn_mfma_f32_16x16x32_bf16(af.v, bfr[ht2][2].v, zero4, 0, 0, 0);
            #pragma unroll
            for (int reg = 0; reg < 4; ++reg) {
                const float gi = ai[reg] + biaL[ht2][0];   // scaled by log2e
                const float gg = ag[reg] + biaL[ht2][1];   // scaled by 2*log2e
                const float go = ao[reg] + biaL[ht2][2];   // scaled by log2e
                const float e1 = aexp2n(gi);               // e^-gi
                const float e2 = aexp2(gg);                // e^2gg
                const float c  = (e2 - 1.f) *
                    __builtin_amdgcn_rcpf((1.f + e1) * (e2 + 1.f));
                const float e3 = aexp2n(go);               // e^-go
                const float e4 = aexp2(c * L2E2_);         // e^2c
                const float hh = (e4 - 1.f) *
                    __builtin_amdgcn_rcpf((1.f + e3) * (e4 + 1.f));
                hd_acc[ht2] = fmaf(hh, xr4[reg], hd_acc[ht2]);
                px[reg]     = fmaf(hh, wshL[ht2], px[reg]);
            }
        }
        #pragma unroll
        for (int reg = 0; reg < 4; ++reg) {
            float pv = px[reg];
            pv += __shfl_xor(pv, 1, 64);
            pv += __shfl_xor(pv, 2, 64);
            pv += __shfl_xor(pv, 4, 64);
            pv += __shfl_xor(pv, 8, 64);
            if (col == 0) xh_part[w][tt * 16 + quad * 4 + reg] = pv;
        }
    }

    // ---- Hd partial -> global (per-half slot, non-atomic) ----
    #pragma unroll
    for (int ht2 = 0; ht2 < 2; ++ht2) {
        float v = hd_acc[ht2];
        v += __shfl_xor(v, 16, 64);
        v += __shfl_xor(v, 32, 64);
        if (lane < 16)
            Hd_part[(((size_t)half * B_ + b) * N_ + n) * H_ + (2 * w + ht2) * 16 + lane] = v;
    }
    // ---- Dinv partial ----
    {
        float dv = (tid < 112) ? xr_loc[tid] : 0.f;
        #pragma unroll
        for (int off = 32; off > 0; off >>= 1) dv += __shfl_down(dv, off, 64);
        if (lane == 0) red[w] = dv;
    }
    __syncthreads();
    if (tid == 0)
        Dinv_part[((size_t)half * B_ + b) * N_ + n] = red[0] + red[1] + red[2] + red[3];

    // ---- X_hat writeout (disjoint t-range per half) ----
    if (tid < 112) {
        const float v = xh_part[0][tid] + xh_part[1][tid] +
                        xh_part[2][tid] + xh_part[3][tid];
        xhat[((size_t)b * TT_ + half * 112 + tid) * N_ + n] = v + bsum_n + 1e-6f;
    }
}

// ---------------------------------------------------------------------------
// Kernel 2 (revived R6 structure): G[b,j,n] = (1/224)*(sum_h W_fc[n,j,h]*Hd +
// b_fc[n,j]*Dinv), Hd/Dinv = sum of the two t-half partials.
// grid (N, 8) = 1024 blocks; 16 j-rows per block.
// ---------------------------------------------------------------------------
__global__ __launch_bounds__(256)
void k_g(const float* __restrict__ W_fc, const float* __restrict__ b_fc,
         const float* __restrict__ Hd_part, const float* __restrict__ Dinv_part,
         float* __restrict__ G) {
    const int n  = blockIdx.x;
    const int j0 = blockIdx.y * 16;
    const int tid = threadIdx.x;

    __shared__ float ws[16][132];
    __shared__ float hd_s[B_][132];
    __shared__ float dinv_s[B_];
    __shared__ float pacc[16][16][8];

    const f4* Wg = (const f4*)(W_fc + ((size_t)n * N_ + j0) * H_);   // 512 f4
    #pragma unroll
    for (int k = 0; k < 2; ++k) {
        const int i = tid + k * 256;
        *(f4*)&ws[i >> 5][(i & 31) * 4] = Wg[i];
    }
    for (int i = tid; i < B_ * H_; i += 256) {
        const int bb = i >> 7, hh = i & 127;
        hd_s[bb][hh] = Hd_part[((size_t)bb * N_ + n) * H_ + hh] +
                       Hd_part[(((size_t)B_ + bb) * N_ + n) * H_ + hh];
    }
    if (tid < B_)
        dinv_s[tid] = Dinv_part[(size_t)tid * N_ + n] +
                      Dinv_part[((size_t)B_ + tid) * N_ + n];
    __syncthreads();

    const int jl = tid >> 4;   // 0..15
    const int cl = tid & 15;   // h-slice of 8
    float acc[B_];
    #pragma unroll
    for (int bb = 0; bb < B_; ++bb) acc[bb] = 0.f;
    #pragma unroll
    for (int q = 0; q < 2; ++q) {
        const f4 wv = *(const f4*)&ws[jl][cl * 8 + q * 4];
        const int hb = cl * 8 + q * 4;
        #pragma unroll
        for (int bb = 0; bb < B_; ++bb) {
            acc[bb] = fmaf(wv.x, hd_s[bb][hb + 0],
                      fmaf(wv.y, hd_s[bb][hb + 1],
                      fmaf(wv.z, hd_s[bb][hb + 2],
                      fmaf(wv.w, hd_s[bb][hb + 3], acc[bb]))));
        }
    }
    #pragma unroll
    for (int bb = 0; bb < B_; ++bb) pacc[jl][cl][bb] = acc[bb];
    __syncthreads();

    if (tid < 128) {
        const int j2 = tid >> 3, bb = tid & 7;
        float s = 0.f;
        #pragma unroll
        for (int c = 0; c < 16; ++c) s += pacc[j2][c][bb];
        const float bj = b_fc[n * N_ + j0 + j2];
        G[(size_t)bb * N_ * N_ + (size_t)(j0 + j2) * N_ + n] =
            (s + bj * dinv_s[bb]) * (1.0f / 224.0f);
    }
}

// ---------------------------------------------------------------------------
extern "C" void kernel_launch(void* const* d_in, const int* in_sizes, int n_in,
                              void* d_out, int out_size, void* d_ws, size_t ws_size,
                              hipStream_t stream) {
    const float* x    = (const float*)d_in[0];
    const float* W_ih = (const float*)d_in[1];
    const float* b_ih = (const float*)d_in[2];
    const float* b_hh = (const float*)d_in[3];
    const float* W_fc = (const float*)d_in[4];
    const float* b_fc = (const float*)d_in[5];

    float* G    = (float*)d_out;                        // B*N*N = 131072
    float* xhat = (float*)d_out + (size_t)B_ * N_ * N_; // B*TT*N = 229376

    unsigned short* W3sw = (unsigned short*)d_ws;             // 128*1536*8 bf16 = 3 MB
    float* wsum   = (float*)(W3sw + (size_t)N_ * 1536 * 8);   // 16384
    float* bsum   = wsum + N_ * H_;                           // 128
    float* bia_g  = bsum + N_;                                // 49152
    float* Hd_p   = bia_g + N_ * 384;                         // 2*B*N*H = 262144
    float* Dinv_p = Hd_p + (size_t)2 * B_ * N_ * H_;          // 2*B*N = 2048

    k_pre<<<dim3(N_, 7), dim3(256), 0, stream>>>(W_ih, W_fc, b_ih, b_hh, b_fc,
                                                 W3sw, wsum, bsum, bia_g);
    k_main<<<dim3(N_, B_, 2), dim3(256), 0, stream>>>(x, W3sw, bia_g, wsum, bsum,
                                                      Hd_p, Dinv_p, xhat);
    k_g<<<dim3(N_, 8), dim3(256), 0, stream>>>(W_fc, b_fc, Hd_p, Dinv_p, G);
}

// Round 12
// 123.416 us; speedup vs baseline: 1.2871x; 1.2871x over previous
//
#include <hip/hip_runtime.h>
#include <math.h>

#define B_  8
#define N_  128
#define T_  256
#define L_  32
#define H_  128
#define TT_ 224   // T - L

typedef float f4    __attribute__((ext_vector_type(4)));
typedef float f32x4 __attribute__((ext_vector_type(4)));
typedef short bf16x8 __attribute__((ext_vector_type(8)));

#define L2E_  1.4426950408889634f
#define L2E2_ 2.8853900817779268f

__device__ __forceinline__ unsigned pk2bf(float a, float b) {   // RNE bf16 pack
    unsigned ua = __float_as_uint(a), ub = __float_as_uint(b);
    ua = (ua + 0x7FFFu + ((ua >> 16) & 1u)) >> 16;
    ub = (ub + 0x7FFFu + ((ub >> 16) & 1u)) >> 16;
    return ua | (ub << 16);
}
__device__ __forceinline__ float aexp2(float x) {
    float r; asm("v_exp_f32 %0, %1" : "=v"(r) : "v"(x)); return r;
}
__device__ __forceinline__ float aexp2n(float x) {
    float r; asm("v_exp_f32 %0, -%1" : "=v"(r) : "v"(x)); return r;
}

// ---------------------------------------------------------------------------
// Kernel 0, grid (N, 7) x 256 (unchanged from R11 — verified):
//  y=0..5: W_ih -> bf16 W3sw pre-swizzled per-lane MFMA B-frag order,
//          PRE-SCALED: gate i,o rows x log2e; gate g rows x 2*log2e.
//  y=6:    wsum / bsum / fused bias (same pre-scale per gate).
// ---------------------------------------------------------------------------
__global__ __launch_bounds__(256)
void k_pre(const float* __restrict__ W_ih, const float* __restrict__ W_fc,
           const float* __restrict__ b_ih, const float* __restrict__ b_hh,
           const float* __restrict__ b_fc,
           unsigned short* __restrict__ W3sw, float* __restrict__ wsum,
           float* __restrict__ bsum, float* __restrict__ bia_g) {
    const int n   = blockIdx.x;
    const int pid = blockIdx.y;   // 0..6
    const int tid = threadIdx.x;
    if (pid < 6) {
        const int idx  = pid * 256 + tid;          // 0..1535
        const int fg   = idx >> 6;                 // 0..23
        const int lane = idx & 63;
        const int col  = lane & 15, quad = lane >> 4;
        const int g    = fg % 3, ht = fg / 3;
        const int r    = g * 128 + ht * 16 + col;
        const int sr   = r + (r >= 128 ? 128 : 0);
        const float sc = (g == 1) ? L2E2_ : L2E_;
        const f4* src = (const f4*)(W_ih + (size_t)n * 512 * L_ + sr * L_ + quad * 8);
        f4 v0 = src[0] * sc, v1 = src[1] * sc;
        uint4 out;
        out.x = pk2bf(v0.x, v0.y); out.y = pk2bf(v0.z, v0.w);
        out.z = pk2bf(v1.x, v1.y); out.w = pk2bf(v1.z, v1.w);
        *(uint4*)&W3sw[((size_t)n * 1536 + idx) * 8] = out;
    } else {
        __shared__ f4 part[8][32];
        __shared__ float bp[2];
        {   // wsum: thread (jg=tid>>5, h4=tid&31) sums 16 j
            const int h4 = tid & 31, jg = tid >> 5;
            const f4* Wf = (const f4*)(W_fc + (size_t)n * N_ * H_) + (size_t)jg * 16 * 32 + h4;
            f4 s = {0.f, 0.f, 0.f, 0.f};
            #pragma unroll
            for (int j = 0; j < 16; ++j) s += Wf[j * 32];
            part[jg][h4] = s;
        }
        if (tid < 128) {   // bsum partials
            float bv = b_fc[n * N_ + tid];
            #pragma unroll
            for (int off = 32; off > 0; off >>= 1) bv += __shfl_down(bv, off, 64);
            if ((tid & 63) == 0) bp[tid >> 6] = bv;
        }
        for (int i = tid; i < 384; i += 256) {
            const int sr = i + (i >= 128 ? 128 : 0);
            const float sc = (i >= 128 && i < 256) ? L2E2_ : L2E_;
            bia_g[n * 384 + i] =
                (b_ih[(size_t)n * 512 + sr] + b_hh[(size_t)n * 512 + sr]) * sc;
        }
        __syncthreads();
        if (tid < 32) {
            f4 s = part[0][tid];
            #pragma unroll
            for (int jg = 1; jg < 8; ++jg) s += part[jg][tid];
            *(f4*)&wsum[n * H_ + tid * 4] = s;
        }
        if (tid == 0) bsum[n] = bp[0] + bp[1];
    }
}

// ---------------------------------------------------------------------------
// Kernel 1: grid (N, B, 2) — t-split for 2048 blocks (8 blocks/CU residency).
// R12 FIX vs R11: waves_per_eu(4,4) — R11's (8) forced VGPR=32 and spilled
// 300 MB to scratch (FETCH 140 MB, HBM 48% peak). At (4,4) the allocator
// produces 64 VGPR (R10-proven); HW residency = min(512/64, LDS-limit) = 8
// blocks/CU — the attribute doesn't cap residency, resources do.
// tanh(c) now a deg-7 odd minimax poly (|c|<=1 structural; |err|<=1.5e-4):
// removes 2 of 6 trans ops per element.
// ---------------------------------------------------------------------------
__global__ __launch_bounds__(256)
__attribute__((amdgpu_waves_per_eu(4, 4)))
void k_main(const float* __restrict__ x,
            const unsigned short* __restrict__ W3sw,
            const float* __restrict__ bia_g,
            const float* __restrict__ wsum, const float* __restrict__ bsum,
            float* __restrict__ Hd_part, float* __restrict__ Dinv_part,
            float* __restrict__ xhat) {
    const int n    = blockIdx.x;
    const int b    = blockIdx.y;
    const int half = blockIdx.z;
    const int tid  = threadIdx.x;
    const int w    = tid >> 6;    // wave 0..3
    const int lane = tid & 63;
    const int col  = lane & 15;   // MFMA m/n index
    const int quad = lane >> 4;   // MFMA k-group / row-group

    __shared__ float xs[258];
    __shared__ unsigned xeo[2][128];   // bf16 pairs: [0]=even-start, [1]=shift-1
    __shared__ float xr_loc[112];
    __shared__ uint4 xA[7 * 64];       // per-lane A-frags for this half
    __shared__ float xh_part[4][112];
    __shared__ float red[4];

    // ---- B-frags: 6 coalesced 16B loads (pre-swizzled, pre-scaled) ----
    const uint4* wsw = (const uint4*)W3sw + (size_t)n * 24 * 64 + lane;
    union { uint4 u; bf16x8 v; } bfr[2][3];
    float biaL[2][3], wshL[2];
    #pragma unroll
    for (int ht2 = 0; ht2 < 2; ++ht2) {
        const int ht = 2 * w + ht2;
        #pragma unroll
        for (int g = 0; g < 3; ++g) {
            bfr[ht2][g].u = wsw[(size_t)(ht * 3 + g) * 64];
            biaL[ht2][g]  = bia_g[n * 384 + g * 128 + ht * 16 + col];
        }
        wshL[ht2] = wsum[n * H_ + ht * 16 + col];
    }
    const float bsum_n = bsum[n];

    // ---- stage x, xr for this half, parity pairs ----
    xs[tid] = x[((size_t)b * N_ + n) * T_ + tid];
    if (tid < 2) xs[256 + tid] = 0.f;
    __syncthreads();
    if (tid < 112) xr_loc[tid] = 1.0f / xs[L_ + half * 112 + tid];
    if (tid < 128) {
        xeo[0][tid] = pk2bf(xs[2 * tid],     xs[2 * tid + 1]);
        xeo[1][tid] = pk2bf(xs[2 * tid + 1], xs[2 * tid + 2]);
    }
    __syncthreads();
    // ---- pre-build per-lane A-frags for this half's 7 ttiles ----
    for (int e = tid; e < 7 * 64; e += 256) {
        const int tt = e >> 6, ln = e & 63;
        const int s  = (half * 7 + tt) * 16 + (ln & 15) + (ln >> 4) * 8;
        const int p  = s & 1, base = s >> 1;
        uint4 v;
        v.x = xeo[p][base + 0]; v.y = xeo[p][base + 1];
        v.z = xeo[p][base + 2]; v.w = xeo[p][base + 3];
        xA[e] = v;
    }
    __syncthreads();

    float hd_acc[2] = {0.f, 0.f};
    const f32x4 zero4 = {0.f, 0.f, 0.f, 0.f};

    #pragma unroll 2
    for (int tt = 0; tt < 7; ++tt) {
        union { uint4 u; bf16x8 v; } af;
        af.u = xA[tt * 64 + lane];          // one clean ds_read_b128

        const f4 xr4 = *(const f4*)&xr_loc[tt * 16 + quad * 4];
        float px[4] = {0.f, 0.f, 0.f, 0.f};

        #pragma unroll
        for (int ht2 = 0; ht2 < 2; ++ht2) {
            f32x4 ai = __builtin_amdgcn_mfma_f32_16x16x32_bf16(af.v, bfr[ht2][0].v, zero4, 0, 0, 0);
            f32x4 ag = __builtin_amdgcn_mfma_f32_16x16x32_bf16(af.v, bfr[ht2][1].v, zero4, 0, 0, 0);
            f32x4 ao = __builtin_amdgcn_mfma_f32_16x16x32_bf16(af.v, bfr[ht2][2].v, zero4, 0, 0, 0);
            #pragma unroll
            for (int reg = 0; reg < 4; ++reg) {
                const float gi = ai[reg] + biaL[ht2][0];   // scaled by log2e
                const float gg = ag[reg] + biaL[ht2][1];   // scaled by 2*log2e
                const float go = ao[reg] + biaL[ht2][2];   // scaled by log2e
                const float e1 = aexp2n(gi);               // e^-gi
                const float e2 = aexp2(gg);                // e^2gg
                const float c  = (e2 - 1.f) *
                    __builtin_amdgcn_rcpf((1.f + e1) * (e2 + 1.f));
                // tanh(c), |c|<=1: deg-7 odd minimax (|err|<=1.5e-4)
                const float t2 = c * c;
                const float th = c * fmaf(t2, fmaf(t2, fmaf(t2, -0.027698f,
                                    0.120833f), -0.331541f), 1.0f);
                const float e3 = aexp2n(go);               // e^-go
                const float hh = th * __builtin_amdgcn_rcpf(1.f + e3);
                hd_acc[ht2] = fmaf(hh, xr4[reg], hd_acc[ht2]);
                px[reg]     = fmaf(hh, wshL[ht2], px[reg]);
            }
        }
        #pragma unroll
        for (int reg = 0; reg < 4; ++reg) {
            float pv = px[reg];
            pv += __shfl_xor(pv, 1, 64);
            pv += __shfl_xor(pv, 2, 64);
            pv += __shfl_xor(pv, 4, 64);
            pv += __shfl_xor(pv, 8, 64);
            if (col == 0) xh_part[w][tt * 16 + quad * 4 + reg] = pv;
        }
    }

    // ---- Hd partial -> global (per-half slot, non-atomic) ----
    #pragma unroll
    for (int ht2 = 0; ht2 < 2; ++ht2) {
        float v = hd_acc[ht2];
        v += __shfl_xor(v, 16, 64);
        v += __shfl_xor(v, 32, 64);
        if (lane < 16)
            Hd_part[(((size_t)half * B_ + b) * N_ + n) * H_ + (2 * w + ht2) * 16 + lane] = v;
    }
    // ---- Dinv partial ----
    {
        float dv = (tid < 112) ? xr_loc[tid] : 0.f;
        #pragma unroll
        for (int off = 32; off > 0; off >>= 1) dv += __shfl_down(dv, off, 64);
        if (lane == 0) red[w] = dv;
    }
    __syncthreads();
    if (tid == 0)
        Dinv_part[((size_t)half * B_ + b) * N_ + n] = red[0] + red[1] + red[2] + red[3];

    // ---- X_hat writeout (disjoint t-range per half) ----
    if (tid < 112) {
        const float v = xh_part[0][tid] + xh_part[1][tid] +
                        xh_part[2][tid] + xh_part[3][tid];
        xhat[((size_t)b * TT_ + half * 112 + tid) * N_ + n] = v + bsum_n + 1e-6f;
    }
}

// ---------------------------------------------------------------------------
// Kernel 2 (verified in R11): G[b,j,n] = (1/224)*(sum_h W_fc[n,j,h]*Hd +
// b_fc[n,j]*Dinv), Hd/Dinv = sum of the two t-half partials.
// grid (N, 8) = 1024 blocks; 16 j-rows per block.
// ---------------------------------------------------------------------------
__global__ __launch_bounds__(256)
void k_g(const float* __restrict__ W_fc, const float* __restrict__ b_fc,
         const float* __restrict__ Hd_part, const float* __restrict__ Dinv_part,
         float* __restrict__ G) {
    const int n  = blockIdx.x;
    const int j0 = blockIdx.y * 16;
    const int tid = threadIdx.x;

    __shared__ float ws[16][132];
    __shared__ float hd_s[B_][132];
    __shared__ float dinv_s[B_];
    __shared__ float pacc[16][16][8];

    const f4* Wg = (const f4*)(W_fc + ((size_t)n * N_ + j0) * H_);   // 512 f4
    #pragma unroll
    for (int k = 0; k < 2; ++k) {
        const int i = tid + k * 256;
        *(f4*)&ws[i >> 5][(i & 31) * 4] = Wg[i];
    }
    for (int i = tid; i < B_ * H_; i += 256) {
        const int bb = i >> 7, hh = i & 127;
        hd_s[bb][hh] = Hd_part[((size_t)bb * N_ + n) * H_ + hh] +
                       Hd_part[(((size_t)B_ + bb) * N_ + n) * H_ + hh];
    }
    if (tid < B_)
        dinv_s[tid] = Dinv_part[(size_t)tid * N_ + n] +
                      Dinv_part[((size_t)B_ + tid) * N_ + n];
    __syncthreads();

    const int jl = tid >> 4;   // 0..15
    const int cl = tid & 15;   // h-slice of 8
    float acc[B_];
    #pragma unroll
    for (int bb = 0; bb < B_; ++bb) acc[bb] = 0.f;
    #pragma unroll
    for (int q = 0; q < 2; ++q) {
        const f4 wv = *(const f4*)&ws[jl][cl * 8 + q * 4];
        const int hb = cl * 8 + q * 4;
        #pragma unroll
        for (int bb = 0; bb < B_; ++bb) {
            acc[bb] = fmaf(wv.x, hd_s[bb][hb + 0],
                      fmaf(wv.y, hd_s[bb][hb + 1],
                      fmaf(wv.z, hd_s[bb][hb + 2],
                      fmaf(wv.w, hd_s[bb][hb + 3], acc[bb]))));
        }
    }
    #pragma unroll
    for (int bb = 0; bb < B_; ++bb) pacc[jl][cl][bb] = acc[bb];
    __syncthreads();

    if (tid < 128) {
        const int j2 = tid >> 3, bb = tid & 7;
        float s = 0.f;
        #pragma unroll
        for (int c = 0; c < 16; ++c) s += pacc[j2][c][bb];
        const float bj = b_fc[n * N_ + j0 + j2];
        G[(size_t)bb * N_ * N_ + (size_t)(j0 + j2) * N_ + n] =
            (s + bj * dinv_s[bb]) * (1.0f / 224.0f);
    }
}

// ---------------------------------------------------------------------------
extern "C" void kernel_launch(void* const* d_in, const int* in_sizes, int n_in,
                              void* d_out, int out_size, void* d_ws, size_t ws_size,
                              hipStream_t stream) {
    const float* x    = (const float*)d_in[0];
    const float* W_ih = (const float*)d_in[1];
    const float* b_ih = (const float*)d_in[2];
    const float* b_hh = (const float*)d_in[3];
    const float* W_fc = (const float*)d_in[4];
    const float* b_fc = (const float*)d_in[5];

    float* G    = (float*)d_out;                        // B*N*N = 131072
    float* xhat = (float*)d_out + (size_t)B_ * N_ * N_; // B*TT*N = 229376

    unsigned short* W3sw = (unsigned short*)d_ws;             // 128*1536*8 bf16 = 3 MB
    float* wsum   = (float*)(W3sw + (size_t)N_ * 1536 * 8);   // 16384
    float* bsum   = wsum + N_ * H_;                           // 128
    float* bia_g  = bsum + N_;                                // 49152
    float* Hd_p   = bia_g + N_ * 384;                         // 2*B*N*H = 262144
    float* Dinv_p = Hd_p + (size_t)2 * B_ * N_ * H_;          // 2*B*N = 2048

    k_pre<<<dim3(N_, 7), dim3(256), 0, stream>>>(W_ih, W_fc, b_ih, b_hh, b_fc,
                                                 W3sw, wsum, bsum, bia_g);
    k_main<<<dim3(N_, B_, 2), dim3(256), 0, stream>>>(x, W3sw, bia_g, wsum, bsum,
                                                      Hd_p, Dinv_p, xhat);
    k_g<<<dim3(N_, 8), dim3(256), 0, stream>>>(W_fc, b_fc, Hd_p, Dinv_p, G);
}

// Round 13
// 110.867 us; speedup vs baseline: 1.4328x; 1.1132x over previous
//
#include <hip/hip_runtime.h>
#include <math.h>

#define B_  8
#define N_  128
#define T_  256
#define L_  32
#define H_  128
#define TT_ 224   // T - L

typedef float f2    __attribute__((ext_vector_type(2)));
typedef float f4    __attribute__((ext_vector_type(4)));
typedef float f32x4 __attribute__((ext_vector_type(4)));
typedef short bf16x8 __attribute__((ext_vector_type(8)));

#define L2E_  1.4426950408889634f
#define L2E2_ 2.8853900817779268f

__device__ __forceinline__ unsigned pk2bf(float a, float b) {   // RNE bf16 pack
    unsigned ua = __float_as_uint(a), ub = __float_as_uint(b);
    ua = (ua + 0x7FFFu + ((ua >> 16) & 1u)) >> 16;
    ub = (ub + 0x7FFFu + ((ub >> 16) & 1u)) >> 16;
    return ua | (ub << 16);
}
__device__ __forceinline__ float aexp2(float x) {
    float r; asm("v_exp_f32 %0, %1" : "=v"(r) : "v"(x)); return r;
}
__device__ __forceinline__ float aexp2n(float x) {
    float r; asm("v_exp_f32 %0, -%1" : "=v"(r) : "v"(x)); return r;
}
__device__ __forceinline__ float arcp(float x) {
    return __builtin_amdgcn_rcpf(x);
}

// ---------------------------------------------------------------------------
// Kernel 0, grid (N, 7) x 256 (verified R11/R12):
//  y=0..5: W_ih -> bf16 W3sw pre-swizzled per-lane MFMA B-frag order,
//          PRE-SCALED: gate i,o rows x log2e; gate g rows x 2*log2e.
//  y=6:    wsum / bsum / fused bias (same pre-scale per gate).
// ---------------------------------------------------------------------------
__global__ __launch_bounds__(256)
void k_pre(const float* __restrict__ W_ih, const float* __restrict__ W_fc,
           const float* __restrict__ b_ih, const float* __restrict__ b_hh,
           const float* __restrict__ b_fc,
           unsigned short* __restrict__ W3sw, float* __restrict__ wsum,
           float* __restrict__ bsum, float* __restrict__ bia_g) {
    const int n   = blockIdx.x;
    const int pid = blockIdx.y;   // 0..6
    const int tid = threadIdx.x;
    if (pid < 6) {
        const int idx  = pid * 256 + tid;          // 0..1535
        const int fg   = idx >> 6;                 // 0..23
        const int lane = idx & 63;
        const int col  = lane & 15, quad = lane >> 4;
        const int g    = fg % 3, ht = fg / 3;
        const int r    = g * 128 + ht * 16 + col;
        const int sr   = r + (r >= 128 ? 128 : 0);
        const float sc = (g == 1) ? L2E2_ : L2E_;
        const f4* src = (const f4*)(W_ih + (size_t)n * 512 * L_ + sr * L_ + quad * 8);
        f4 v0 = src[0] * sc, v1 = src[1] * sc;
        uint4 out;
        out.x = pk2bf(v0.x, v0.y); out.y = pk2bf(v0.z, v0.w);
        out.z = pk2bf(v1.x, v1.y); out.w = pk2bf(v1.z, v1.w);
        *(uint4*)&W3sw[((size_t)n * 1536 + idx) * 8] = out;
    } else {
        __shared__ f4 part[8][32];
        __shared__ float bp[2];
        {   // wsum: thread (jg=tid>>5, h4=tid&31) sums 16 j
            const int h4 = tid & 31, jg = tid >> 5;
            const f4* Wf = (const f4*)(W_fc + (size_t)n * N_ * H_) + (size_t)jg * 16 * 32 + h4;
            f4 s = {0.f, 0.f, 0.f, 0.f};
            #pragma unroll
            for (int j = 0; j < 16; ++j) s += Wf[j * 32];
            part[jg][h4] = s;
        }
        if (tid < 128) {   // bsum partials
            float bv = b_fc[n * N_ + tid];
            #pragma unroll
            for (int off = 32; off > 0; off >>= 1) bv += __shfl_down(bv, off, 64);
            if ((tid & 63) == 0) bp[tid >> 6] = bv;
        }
        for (int i = tid; i < 384; i += 256) {
            const int sr = i + (i >= 128 ? 128 : 0);
            const float sc = (i >= 128 && i < 256) ? L2E2_ : L2E_;
            bia_g[n * 384 + i] =
                (b_ih[(size_t)n * 512 + sr] + b_hh[(size_t)n * 512 + sr]) * sc;
        }
        __syncthreads();
        if (tid < 32) {
            f4 s = part[0][tid];
            #pragma unroll
            for (int jg = 1; jg < 8; ++jg) s += part[jg][tid];
            *(f4*)&wsum[n * H_ + tid * 4] = s;
        }
        if (tid == 0) bsum[n] = bp[0] + bp[1];
    }
}

// ---------------------------------------------------------------------------
// Kernel 1: R10 structure (grid (N,B)=1024, fused G epilogue — best total at
// 114.5; R12's t-split+k_g bought nothing). Activation: 4 trans/element
// (was 5) via merged reciprocal, exact algebra:
//   A=(1+e1)(e2+1), B=1+e3, R=rcp(A*B), t=em*R (em=e2-1),
//   c=t*B (= sig(gi)tanh(gg)), hh=t*Q(c^2) (= sig(go)*poly7tanh(c)).
// FMA chain done on float2 pairs to invite v_pk_*_f32 packing.
// ---------------------------------------------------------------------------
__global__ __launch_bounds__(256)
__attribute__((amdgpu_waves_per_eu(4, 4)))
void k_main(const float* __restrict__ x,
            const unsigned short* __restrict__ W3sw,
            const float* __restrict__ bia_g,
            const float* __restrict__ wsum, const float* __restrict__ bsum,
            const float* __restrict__ W_fc, const float* __restrict__ b_fc,
            float* __restrict__ G, float* __restrict__ xhat) {
    const int n   = blockIdx.x;
    const int b   = blockIdx.y;
    const int tid = threadIdx.x;
    const int w    = tid >> 6;    // wave 0..3
    const int lane = tid & 63;
    const int col  = lane & 15;   // MFMA m/n index
    const int quad = lane >> 4;   // MFMA k-group / row-group

    __shared__ float xs[258];
    __shared__ unsigned xeo[2][128];
    __shared__ float xr[TT_];
    __shared__ uint4 xA[14 * 64];      // per-lane A-frags, 14 KB
    __shared__ float xh_part[4][TT_];
    __shared__ float hd_loc[H_];
    __shared__ float red[4];

    // ---- B-frags: 6 coalesced 16B loads (pre-swizzled, pre-scaled) ----
    const uint4* wsw = (const uint4*)W3sw + (size_t)n * 24 * 64 + lane;
    union { uint4 u; bf16x8 v; } bfr[2][3];
    float biaL[2][3], wshL[2];
    #pragma unroll
    for (int ht2 = 0; ht2 < 2; ++ht2) {
        const int ht = 2 * w + ht2;
        #pragma unroll
        for (int g = 0; g < 3; ++g) {
            bfr[ht2][g].u = wsw[(size_t)(ht * 3 + g) * 64];
            biaL[ht2][g]  = bia_g[n * 384 + g * 128 + ht * 16 + col];
        }
        wshL[ht2] = wsum[n * H_ + ht * 16 + col];
    }
    const float bsum_n = bsum[n];

    // ---- stage x ----
    xs[tid] = x[((size_t)b * N_ + n) * T_ + tid];
    if (tid < 2) xs[256 + tid] = 0.f;
    __syncthreads();
    if (tid < TT_) xr[tid] = 1.0f / xs[L_ + tid];
    if (tid < 128) {
        xeo[0][tid] = pk2bf(xs[2 * tid],     xs[2 * tid + 1]);
        xeo[1][tid] = pk2bf(xs[2 * tid + 1], xs[2 * tid + 2]);
    }
    __syncthreads();
    // ---- pre-build per-lane A-frags (conflicted pattern paid once) ----
    for (int e = tid; e < 14 * 64; e += 256) {
        const int tt = e >> 6, ln = e & 63;
        const int s  = tt * 16 + (ln & 15) + (ln >> 4) * 8;
        const int p  = s & 1, base = s >> 1;
        uint4 v;
        v.x = xeo[p][base + 0]; v.y = xeo[p][base + 1];
        v.z = xeo[p][base + 2]; v.w = xeo[p][base + 3];
        xA[e] = v;
    }
    __syncthreads();

    float hd_acc[2] = {0.f, 0.f};
    const f32x4 zero4 = {0.f, 0.f, 0.f, 0.f};

    #pragma unroll 2
    for (int ttile = 0; ttile < 14; ++ttile) {
        union { uint4 u; bf16x8 v; } af;
        af.u = xA[ttile * 64 + lane];          // one clean ds_read_b128

        const f4 xr4 = *(const f4*)&xr[ttile * 16 + quad * 4];
        float px[4];

        #pragma unroll
        for (int ht2 = 0; ht2 < 2; ++ht2) {
            f32x4 ai = __builtin_amdgcn_mfma_f32_16x16x32_bf16(af.v, bfr[ht2][0].v, zero4, 0, 0, 0);
            f32x4 ag = __builtin_amdgcn_mfma_f32_16x16x32_bf16(af.v, bfr[ht2][1].v, zero4, 0, 0, 0);
            f32x4 ao = __builtin_amdgcn_mfma_f32_16x16x32_bf16(af.v, bfr[ht2][2].v, zero4, 0, 0, 0);
            #pragma unroll
            for (int pr = 0; pr < 2; ++pr) {
                f2 gi = {ai[2*pr] + biaL[ht2][0], ai[2*pr+1] + biaL[ht2][0]};
                f2 gg = {ag[2*pr] + biaL[ht2][1], ag[2*pr+1] + biaL[ht2][1]};
                f2 go = {ao[2*pr] + biaL[ht2][2], ao[2*pr+1] + biaL[ht2][2]};
                f2 e1 = {aexp2n(gi.x), aexp2n(gi.y)};   // e^-gi
                f2 e2 = {aexp2(gg.x),  aexp2(gg.y)};    // e^2gg
                f2 e3 = {aexp2n(go.x), aexp2n(go.y)};   // e^-go
                const f2 A  = (1.f + e1) * (e2 + 1.f);
                const f2 Bv = 1.f + e3;
                const f2 AB = A * Bv;
                f2 R  = {arcp(AB.x), arcp(AB.y)};       // single merged rcp
                const f2 em = e2 - 1.f;
                const f2 t  = em * R;
                const f2 c  = t * Bv;                   // sig(gi)*tanh(gg)
                const f2 c2 = c * c;
                // tanh(c), |c|<=1: deg-7 odd (R12-verified coeffs)
                f2 Q = c2 * -0.027698f + 0.120833f;
                Q = c2 * Q - 0.331541f;
                Q = c2 * Q + 1.0f;
                const f2 hh = t * (Q * c);              // wait: hh = t*Q? see below
                // NOTE: poly7(c) = c*Q(c2); hh = poly7(c)/B = (c/B)*Q = t*em?  —
                // c/B = t, so hh = t*Q. The (Q*c) above would be wrong; fix:
                const f2 hhv = t * Q;
                hd_acc[ht2] = fmaf(hhv.x, xr4[2*pr],   hd_acc[ht2]);
                hd_acc[ht2] = fmaf(hhv.y, xr4[2*pr+1], hd_acc[ht2]);
                px[2*pr]   = hhv.x * wshL[ht2] + (ht2 ? px[2*pr]   : 0.f);
                px[2*pr+1] = hhv.y * wshL[ht2] + (ht2 ? px[2*pr+1] : 0.f);
                (void)hh;
            }
        }
        // X_hat partial: sum over this wave's 32 h (in-lane) then 16 n-lanes
        #pragma unroll
        for (int reg = 0; reg < 4; ++reg) {
            float pv = px[reg];
            pv += __shfl_xor(pv, 1, 64);
            pv += __shfl_xor(pv, 2, 64);
            pv += __shfl_xor(pv, 4, 64);
            pv += __shfl_xor(pv, 8, 64);
            if (col == 0) xh_part[w][ttile * 16 + quad * 4 + reg] = pv;
        }
    }

    // ---- Hd -> LDS (reduce across quads), Dinv partials ----
    #pragma unroll
    for (int ht2 = 0; ht2 < 2; ++ht2) {
        float v = hd_acc[ht2];
        v += __shfl_xor(v, 16, 64);
        v += __shfl_xor(v, 32, 64);
        if (lane < 16) hd_loc[(2 * w + ht2) * 16 + lane] = v;
    }
    {
        float dv = (tid < TT_) ? xr[tid] : 0.f;
        #pragma unroll
        for (int off = 32; off > 0; off >>= 1) dv += __shfl_down(dv, off, 64);
        if (lane == 0) red[w] = dv;
    }
    __syncthreads();

    // ---- X_hat writeout ----
    if (tid < TT_) {
        const float v = xh_part[0][tid] + xh_part[1][tid] +
                        xh_part[2][tid] + xh_part[3][tid];
        xhat[((size_t)b * TT_ + tid) * N_ + n] = v + bsum_n + 1e-6f;
    }

    // ---- fused G epilogue: thread pair (j, half) sums 64 h each ----
    {
        const float dinv = red[0] + red[1] + red[2] + red[3];
        const int j    = tid >> 1;
        const int half = tid & 1;
        const f4* Wf = (const f4*)(W_fc + ((size_t)n * N_ + j) * H_ + half * 64);
        float s = 0.f;
        #pragma unroll
        for (int q = 0; q < 16; ++q) {
            const f4 wv = Wf[q];
            const int hb = half * 64 + q * 4;
            s = fmaf(wv.x, hd_loc[hb + 0],
                fmaf(wv.y, hd_loc[hb + 1],
                fmaf(wv.z, hd_loc[hb + 2],
                fmaf(wv.w, hd_loc[hb + 3], s))));
        }
        s += __shfl_xor(s, 1, 64);
        if (half == 0) {
            const float bj = b_fc[n * N_ + j];
            G[(size_t)b * N_ * N_ + (size_t)j * N_ + n] =
                (s + bj * dinv) * (1.0f / 224.0f);
        }
    }
}

// ---------------------------------------------------------------------------
extern "C" void kernel_launch(void* const* d_in, const int* in_sizes, int n_in,
                              void* d_out, int out_size, void* d_ws, size_t ws_size,
                              hipStream_t stream) {
    const float* x    = (const float*)d_in[0];
    const float* W_ih = (const float*)d_in[1];
    const float* b_ih = (const float*)d_in[2];
    const float* b_hh = (const float*)d_in[3];
    const float* W_fc = (const float*)d_in[4];
    const float* b_fc = (const float*)d_in[5];

    float* G    = (float*)d_out;                        // B*N*N = 131072
    float* xhat = (float*)d_out + (size_t)B_ * N_ * N_; // B*TT*N = 229376

    unsigned short* W3sw = (unsigned short*)d_ws;             // 128*1536*8 bf16 = 3 MB
    float* wsum   = (float*)(W3sw + (size_t)N_ * 1536 * 8);   // 16384
    float* bsum   = wsum + N_ * H_;                           // 128
    float* bia_g  = bsum + N_;                                // 49152

    k_pre<<<dim3(N_, 7), dim3(256), 0, stream>>>(W_ih, W_fc, b_ih, b_hh, b_fc,
                                                 W3sw, wsum, bsum, bia_g);
    k_main<<<dim3(N_, B_), dim3(256), 0, stream>>>(x, W3sw, bia_g, wsum, bsum,
                                                   W_fc, b_fc, G, xhat);
}